// Round 2
// baseline (198.762 us; speedup 1.0000x reference)
//
#include <hip/hip_runtime.h>
#include <cstdint>
#include <cstddef>

// ---------------------------------------------------------------------------
// ChatGPTAttention: x[2,2048,1024] -> QKV proj -> causal MHA (16 heads, dk=64)
//                   -> O proj. bf16 MFMA pipeline, fp32 accumulate.
// Q pre-scaled by 1/8 in QKV-GEMM epilogue; V written transposed by the same
// epilogue (transpose_v eliminated, R14).
// LESSONS: (R5) LDS row stride multiple of 8 ushorts. (R6/R8) XOR swizzle for
// DMA-staged LDS. (R8/R9) dbuf DMA needs occupancy preserved. (R11/R15)
// direct global frags: V rows OK at 1x, K rows serialize — stage K. (R12/R13)
// 1-wave = one latency chain. (R15) split-K dead. (R16/R17 A/B) attn dur
// identical at 2 vs 4 blocks/CU. (R18 v14) split P buffers + tail reorder.
// (R19 v15 FAILED) lag-1 PV: held frags across barrier spilled (VGPR stuck
// at 88), pre-barrier ds_reads lengthened barrier path; 43.2->46.9us. REVERTED.
// R20 v16: LDS-BW MODEL. v14 arithmetic: 66 tiles/CU, 524 cyc/tile/CU
// throughput == 64KB/tile LDS traffic / 128B/cyc. LDS bandwidth is the
// binding per-CU resource (explains R16/R17 occupancy null). Fix: V frags
// read DIRECT from global (vt rows 64B-contiguous/lane, L2-resident via
// XCD swizzle; R11/R15 proved 1x) — removes 8KB DMA write + 16KB dup wave
// reads per tile (64->40KB). V loads issued right after barrier; latency
// hides under S^T+exp. LDS 41->25.6KB.
// ---------------------------------------------------------------------------

typedef __attribute__((ext_vector_type(8))) short bf16x8;   // MFMA A/B frag
typedef __attribute__((ext_vector_type(4))) float f32x4;    // MFMA C/D frag
typedef __attribute__((ext_vector_type(4))) unsigned int u32x4;   // 16B copy
typedef __attribute__((ext_vector_type(4))) unsigned short u16x4; // 8B store
typedef __attribute__((ext_vector_type(8))) unsigned short u16x8; // 16B store

__device__ __forceinline__ unsigned short f2b(float f) {  // RNE f32->bf16
  unsigned int u = __float_as_uint(f);
  u = u + 0x7FFFu + ((u >> 16) & 1u);
  return (unsigned short)(u >> 16);
}
__device__ __forceinline__ unsigned short f2b_trunc(float f) {  // truncate
  return (unsigned short)(__float_as_uint(f) >> 16);
}

// async global->LDS DMA, 16B per lane; LDS dest = wave base + lane*16
__device__ __forceinline__ void gl_lds16(const unsigned short* g, unsigned short* s) {
  __builtin_amdgcn_global_load_lds((const __attribute__((address_space(1))) void*)g,
                                   (__attribute__((address_space(3))) void*)s, 16, 0, 0);
}

// ---------------- fp32 -> bf16, all three inputs in one launch -------------
__global__ __launch_bounds__(256) void cvt_all(const float* __restrict__ x,
                                               const float* __restrict__ wq,
                                               const float* __restrict__ wo,
                                               unsigned short* __restrict__ xb,
                                               unsigned short* __restrict__ wqb,
                                               unsigned short* __restrict__ wob) {
  const int bid = blockIdx.x;
  const float* in;
  unsigned short* out;
  int base;
  if (bid < 4096)      { in = x;  out = xb;  base = bid; }
  else if (bid < 7168) { in = wq; out = wqb; base = bid - 4096; }
  else                 { in = wo; out = wob; base = bid - 7168; }
  const int idx = (base * 256 + threadIdx.x) * 4;
  f32x4 v = *(const f32x4*)(in + idx);
  u16x4 r;
  r[0] = f2b(v[0]); r[1] = f2b(v[1]); r[2] = f2b(v[2]); r[3] = f2b(v[3]);
  *(u16x4*)(out + idx) = r;
}

// ---------------- GEMM: C[M,N] = (A[M,K] * W[N,K]^T + bias) * colscale -----
// 128x128 tile, BK=32, dbuf DMA (32KB LDS). V-column blocks (n0>=2048) write
// transposed into vt as packed u16x4. Unchanged from R14.
__global__ __launch_bounds__(256) void gemm_bt(const unsigned short* __restrict__ A,
                                               const unsigned short* __restrict__ W,
                                               const float* __restrict__ bias,
                                               unsigned short* __restrict__ Cb,
                                               unsigned short* __restrict__ vtb,
                                               int M, int N, int K, int qcols) {
  __shared__ unsigned short As[2][128 * 32];
  __shared__ unsigned short Bs[2][128 * 32];
  const int tid  = threadIdx.x;
  const int lane = tid & 63;
  const int w    = tid >> 6;
  const int wy   = w >> 1, wx = w & 1;
  const int l15  = lane & 15, quad = lane >> 4;
  const int xr2  = (l15 >> 1) & 3;
  const int m0 = blockIdx.y * 128, n0 = blockIdx.x * 128;

  const unsigned short* gA[2];
  const unsigned short* gB[2];
  int off[2];
#pragma unroll
  for (int p = 0; p < 2; ++p) {
    const int c = tid + p * 256;
    const int r = c >> 2;
    const int srcc = (c & 3) ^ ((r >> 1) & 3);
    gA[p] = A + (size_t)(m0 + r) * K + srcc * 8;
    gB[p] = W + (size_t)(n0 + r) * K + srcc * 8;
    off[p] = c * 8;
  }

  f32x4 acc[4][4];
#pragma unroll
  for (int i = 0; i < 4; ++i)
#pragma unroll
    for (int j = 0; j < 4; ++j) acc[i][j] = (f32x4){0.f, 0.f, 0.f, 0.f};

#pragma unroll
  for (int p = 0; p < 2; ++p) {
    gl_lds16(gA[p], &As[0][off[p]]);
    gl_lds16(gB[p], &Bs[0][off[p]]);
  }

  const int NIT = K >> 5;
  for (int it = 0; it < NIT; ++it) {
    __syncthreads();
    const int cur = it & 1;
    if (it + 1 < NIT) {
      const int kt = (it + 1) << 5;
#pragma unroll
      for (int p = 0; p < 2; ++p) {
        gl_lds16(gA[p] + kt, &As[cur ^ 1][off[p]]);
        gl_lds16(gB[p] + kt, &Bs[cur ^ 1][off[p]]);
      }
    }
    const unsigned short* Ac = As[cur];
    const unsigned short* Bc = Bs[cur];
    bf16x8 af[4], bfr[4];
#pragma unroll
    for (int i = 0; i < 4; ++i)
      af[i] = *(const bf16x8*)&Ac[(wy * 64 + i * 16 + l15) * 32 + (quad ^ xr2) * 8];
#pragma unroll
    for (int j = 0; j < 4; ++j)
      bfr[j] = *(const bf16x8*)&Bc[(wx * 64 + j * 16 + l15) * 32 + (quad ^ xr2) * 8];
#pragma unroll
    for (int i = 0; i < 4; ++i)
#pragma unroll
      for (int j = 0; j < 4; ++j)
        acc[i][j] = __builtin_amdgcn_mfma_f32_16x16x32_bf16(af[i], bfr[j], acc[i][j], 0, 0, 0);
  }

  const bool vblock = (n0 >= 2048);  // block-uniform
#pragma unroll
  for (int i = 0; i < 4; ++i) {
    const int row = m0 + wy * 64 + i * 16 + quad * 4;
#pragma unroll
    for (int j = 0; j < 4; ++j) {
      const int col = n0 + wx * 64 + j * 16 + l15;
      const float bv = bias[col];
      if (!vblock) {
        const float sc = (col < qcols) ? 0.125f : 1.0f;
#pragma unroll
        for (int r = 0; r < 4; ++r)
          Cb[(size_t)(row + r) * N + col] = f2b((acc[i][j][r] + bv) * sc);
      } else {
        const int hd = col - 2048;
        const int bb = row >> 11, s = row & 2047;
        u16x4 ov;
#pragma unroll
        for (int r = 0; r < 4; ++r) ov[r] = f2b(acc[i][j][r] + bv);
        *(u16x4*)(vtb + ((size_t)(bb * 1024 + hd)) * 2048 + s) = ov;
      }
    }
  }
}

// ---------------- GEMM 64x64 tile, fp32 out (O-projection) -----------------
// Grid 16x64 = 1024 blocks. BK=64 dbuf (32KB LDS, 4 blocks/CU). R17 config.
__global__ __launch_bounds__(256) void gemm_bt64(const unsigned short* __restrict__ A,
                                                 const unsigned short* __restrict__ W,
                                                 const float* __restrict__ bias,
                                                 float* __restrict__ Cf,
                                                 int M, int N, int K) {
  __shared__ unsigned short As[2][64 * 64];
  __shared__ unsigned short Bs[2][64 * 64];
  const int tid  = threadIdx.x;
  const int lane = tid & 63;
  const int w    = tid >> 6;
  const int wy   = w >> 1, wx = w & 1;
  const int l15  = lane & 15, quad = lane >> 4;
  const int xr   = l15 & 7;
  const int m0 = blockIdx.y * 64, n0 = blockIdx.x * 64;

  const unsigned short* gA[2];
  const unsigned short* gB[2];
  int off[2];
#pragma unroll
  for (int p = 0; p < 2; ++p) {
    const int c = tid + p * 256;
    const int r = c >> 3;
    const int sc = ((c & 7) ^ (r & 7)) * 8;
    gA[p] = A + (size_t)(m0 + r) * K + sc;
    gB[p] = W + (size_t)(n0 + r) * K + sc;
    off[p] = c * 8;
  }

  f32x4 acc[2][2];
#pragma unroll
  for (int i = 0; i < 2; ++i)
#pragma unroll
    for (int j = 0; j < 2; ++j) acc[i][j] = (f32x4){0.f, 0.f, 0.f, 0.f};

#pragma unroll
  for (int p = 0; p < 2; ++p) {
    gl_lds16(gA[p], &As[0][off[p]]);
    gl_lds16(gB[p], &Bs[0][off[p]]);
  }

  const int NIT = K >> 6;
  for (int it = 0; it < NIT; ++it) {
    __syncthreads();
    const int cur = it & 1;
    if (it + 1 < NIT) {
      const int kt = (it + 1) << 6;
#pragma unroll
      for (int p = 0; p < 2; ++p) {
        gl_lds16(gA[p] + kt, &As[cur ^ 1][off[p]]);
        gl_lds16(gB[p] + kt, &Bs[cur ^ 1][off[p]]);
      }
    }
    const unsigned short* Ac = As[cur];
    const unsigned short* Bc = Bs[cur];
#pragma unroll
    for (int kc = 0; kc < 2; ++kc) {
      bf16x8 af[2], bfr[2];
#pragma unroll
      for (int i = 0; i < 2; ++i)
        af[i] = *(const bf16x8*)&Ac[(wy * 32 + i * 16 + l15) * 64 + ((kc * 4 + quad) ^ xr) * 8];
#pragma unroll
      for (int j = 0; j < 2; ++j)
        bfr[j] = *(const bf16x8*)&Bc[(wx * 32 + j * 16 + l15) * 64 + ((kc * 4 + quad) ^ xr) * 8];
#pragma unroll
      for (int i = 0; i < 2; ++i)
#pragma unroll
        for (int j = 0; j < 2; ++j)
          acc[i][j] = __builtin_amdgcn_mfma_f32_16x16x32_bf16(af[i], bfr[j], acc[i][j], 0, 0, 0);
    }
  }

#pragma unroll
  for (int i = 0; i < 2; ++i) {
    const int row = m0 + wy * 32 + i * 16 + quad * 4;
#pragma unroll
    for (int j = 0; j < 2; ++j) {
      const int col = n0 + wx * 32 + j * 16 + l15;
      const float bv = bias[col];
#pragma unroll
      for (int r = 0; r < 4; ++r)
        Cf[(size_t)(row + r) * N + col] = acc[i][j][r] + bv;
    }
  }
}

// ---------------- flash attention v16: v14 + direct-global V ---------------
// Block = 2 waves x 32 q = 64 q; grid (bh 32, qt 32) = 1024 blocks. K staged
// via DMA dbuf XOR-swizzled LDS; V frags read DIRECT from global vt (rows
// 64B-contiguous per lane, L2-resident: XCD=bh%8 keeps each bh's K/V in one
// XCD's L2). S^T=KQ^T, O^T=V^T P^T, no-max softmax, l via ones-A MFMA, LPT
// qt=31-y. v14 tail order preserved: exp0,Pw0,exp1,Pw1,Pr0,PV0,Pr1,PV1.
// LDS 25.6KB (Ks dbuf 16K + pbuf 9K).
__global__ __launch_bounds__(128, 2) void attn_fwd(const unsigned short* __restrict__ qkv,
                                                   const unsigned short* __restrict__ vt,
                                                   unsigned short* __restrict__ o) {
  __shared__ unsigned short Ks[2][64 * 64];
  __shared__ unsigned short pbuf[2][2][16 * 72];  // [wave][subtile][16x72]
  const int tid  = threadIdx.x;
  const int lane = tid & 63;
  const int w    = tid >> 6;          // 2 waves
  const int l15  = lane & 15, quad = lane >> 4;
  const int xr   = l15 & 7;
  const int bh = blockIdx.x, b = bh >> 4, h = bh & 15;
  const int qt = 31 - (int)blockIdx.y;  // LPT order (64-q tiles)
  const int q0 = qt * 64;
  const int qa = q0 + w * 32;
  const int qb = qa + 16;
  const int T = qt + 1;

  // K DMA staging: 512 chunks per 64x64 tile / 128 threads = 4/thread.
  const unsigned short* gKd[4];
  int doff[4];
#pragma unroll
  for (int p = 0; p < 4; ++p) {
    const int c = tid + p * 128;
    const int r = c >> 3;
    const int sc = ((c & 7) ^ (r & 7)) * 8;
    gKd[p] = qkv + (size_t)(b * 2048 + r) * 3072 + 1024 + h * 64 + sc;
    doff[p] = c * 8;
  }

  // V row bases (direct global): row = bh*64 + j*16 + l15, stride 2048.
  const unsigned short* vrow[4];
#pragma unroll
  for (int j = 0; j < 4; ++j)
    vrow[j] = vt + (size_t)(bh * 64 + j * 16 + l15) * 2048;

  const unsigned short* qra = qkv + (size_t)(b * 2048 + qa + l15) * 3072 + h * 64;
  const unsigned short* qrb = qkv + (size_t)(b * 2048 + qb + l15) * 3072 + h * 64;
  const bf16x8 bq[2][2] = {
    { *(const bf16x8*)(qra + quad * 8), *(const bf16x8*)(qra + 32 + quad * 8) },
    { *(const bf16x8*)(qrb + quad * 8), *(const bf16x8*)(qrb + 32 + quad * 8) } };

  bf16x8 vones;
#pragma unroll
  for (int k = 0; k < 8; ++k) vones[k] = (short)0x3F80;  // bf16 1.0

  f32x4 acc[2][4];   // [q-subtile][d-tile] — O^T C-layout: col=q(l15), row=d
#pragma unroll
  for (int i = 0; i < 2; ++i)
#pragma unroll
    for (int j = 0; j < 4; ++j) acc[i][j] = (f32x4){0.f, 0.f, 0.f, 0.f};
  f32x4 accL[2] = {(f32x4){0.f, 0.f, 0.f, 0.f}, (f32x4){0.f, 0.f, 0.f, 0.f}};

  unsigned short* P0 = pbuf[w][0];
  unsigned short* P1 = pbuf[w][1];

  // prologue: DMA K tile 0 -> buf 0
#pragma unroll
  for (int p = 0; p < 4; ++p) gl_lds16(gKd[p], &Ks[0][doff[p]]);

  for (int t = 0; t < T; ++t) {
    __syncthreads();  // drains DMA for buf(t&1)
    const int cur = t & 1;
    if (t + 1 < T) {
      const size_t ko = (size_t)(t + 1) * 64 * 3072;
#pragma unroll
      for (int p = 0; p < 4; ++p)
        gl_lds16(gKd[p] + ko, &Ks[cur ^ 1][doff[p]]);
    }
    const int kv0 = t * 64;
    // ---- V(t) A-frags direct from global, issued EARLY: ~200-300cyc L2
    // latency hides under S^T MFMAs + exp chain; consumed at PV. ----
    bf16x8 av[4][2];
#pragma unroll
    for (int j = 0; j < 4; ++j) {
      av[j][0] = *(const bf16x8*)(vrow[j] + kv0 + quad * 8);
      av[j][1] = *(const bf16x8*)(vrow[j] + kv0 + 32 + quad * 8);
    }
    const unsigned short* Kc = Ks[cur];

    // ---- S^T[kv][q] = K Q^T for both q-subtiles (K frags swizzled) ----
    f32x4 st[2][4];
#pragma unroll
    for (int n = 0; n < 4; ++n) {
      const int row = n * 16 + l15;
      const bf16x8 kA0 = *(const bf16x8*)&Kc[row * 64 + ((quad) ^ xr) * 8];
      const bf16x8 kA1 = *(const bf16x8*)&Kc[row * 64 + ((4 + quad) ^ xr) * 8];
      f32x4 z0 = (f32x4){0.f, 0.f, 0.f, 0.f};
      z0 = __builtin_amdgcn_mfma_f32_16x16x32_bf16(kA0, bq[0][0], z0, 0, 0, 0);
      z0 = __builtin_amdgcn_mfma_f32_16x16x32_bf16(kA1, bq[0][1], z0, 0, 0, 0);
      st[0][n] = z0;
      f32x4 z1 = (f32x4){0.f, 0.f, 0.f, 0.f};
      z1 = __builtin_amdgcn_mfma_f32_16x16x32_bf16(kA0, bq[1][0], z1, 0, 0, 0);
      z1 = __builtin_amdgcn_mfma_f32_16x16x32_bf16(kA1, bq[1][1], z1, 0, 0, 0);
      st[1][n] = z1;
    }
    // ---- mask/exp + P writes for BOTH subtiles (separate buffers) ----
#pragma unroll
    for (int tq = 0; tq < 2; ++tq) {
      unsigned short* P = tq ? P1 : P0;
      const int qbase = tq ? qb : qa;
      if (kv0 + 63 > qbase) {
        const int qrow = qbase + l15;
#pragma unroll
        for (int n = 0; n < 4; ++n)
#pragma unroll
          for (int r = 0; r < 4; ++r)
            if (kv0 + n * 16 + quad * 4 + r > qrow) st[tq][n][r] = -1e30f;
      }
#pragma unroll
      for (int n = 0; n < 4; ++n) {
#pragma unroll
        for (int r = 0; r < 4; ++r) st[tq][n][r] = __expf(st[tq][n][r]);
        u16x4 pw;
        pw[0] = f2b_trunc(st[tq][n][0]); pw[1] = f2b_trunc(st[tq][n][1]);
        pw[2] = f2b_trunc(st[tq][n][2]); pw[3] = f2b_trunc(st[tq][n][3]);
        *(u16x4*)&P[l15 * 72 + n * 16 + quad * 4] = pw;
      }
    }
    // ---- PV for both subtiles (reads pipeline behind the writes) ----
#pragma unroll
    for (int tq = 0; tq < 2; ++tq) {
      const unsigned short* P = tq ? P1 : P0;
      const bf16x8 bp0 = *(const bf16x8*)&P[l15 * 72 + quad * 8];
      const bf16x8 bp1 = *(const bf16x8*)&P[l15 * 72 + 32 + quad * 8];
      accL[tq] = __builtin_amdgcn_mfma_f32_16x16x32_bf16(vones, bp0, accL[tq], 0, 0, 0);
      accL[tq] = __builtin_amdgcn_mfma_f32_16x16x32_bf16(vones, bp1, accL[tq], 0, 0, 0);
#pragma unroll
      for (int j = 0; j < 4; ++j) {
        acc[tq][j] = __builtin_amdgcn_mfma_f32_16x16x32_bf16(av[j][0], bp0, acc[tq][j], 0, 0, 0);
        acc[tq][j] = __builtin_amdgcn_mfma_f32_16x16x32_bf16(av[j][1], bp1, acc[tq][j], 0, 0, 0);
      }
    }
  }
  // ---- epilogue: lane holds q=l15, d=j*16+quad*4+r -> packed u16x4 ----
#pragma unroll
  for (int tq = 0; tq < 2; ++tq) {
    const int qrow = (tq ? qb : qa) + l15;
    const float inv = 1.0f / accL[tq][0];  // all rows of accL equal l[q]
    unsigned short* orow = o + (size_t)(b * 2048 + qrow) * 1024 + h * 64;
#pragma unroll
    for (int j = 0; j < 4; ++j) {
      u16x4 ov;
      ov[0] = f2b(acc[tq][j][0] * inv); ov[1] = f2b(acc[tq][j][1] * inv);
      ov[2] = f2b(acc[tq][j][2] * inv); ov[3] = f2b(acc[tq][j][3] * inv);
      *(u16x4*)(orow + j * 16 + quad * 4) = ov;
    }
  }
}

// ---------------------------------------------------------------------------
extern "C" void kernel_launch(void* const* d_in, const int* in_sizes, int n_in,
                              void* d_out, int out_size, void* d_ws, size_t ws_size,
                              hipStream_t stream) {
  const float* x       = (const float*)d_in[0];
  // d_in[1] = mask: causal tril by construction; implemented analytically.
  const float* w_qkv_w = (const float*)d_in[2];
  const float* w_qkv_b = (const float*)d_in[3];
  const float* w_o_w   = (const float*)d_in[4];
  const float* w_o_b   = (const float*)d_in[5];
  float* out = (float*)d_out;

  unsigned short* ws    = (unsigned short*)d_ws;
  unsigned short* xb    = ws;                                  // 4096*1024
  unsigned short* wqb   = xb   + (size_t)4096 * 1024;          // 3072*1024
  unsigned short* wob   = wqb  + (size_t)3072 * 1024;          // 1024*1024
  unsigned short* qkvb  = wob  + (size_t)1024 * 1024;          // 4096*3072
  unsigned short* vtb   = qkvb + (size_t)4096 * 3072;          // 2048*2048
  unsigned short* attnb = vtb  + (size_t)2048 * 2048;          // 4096*1024

  cvt_all<<<8192, 256, 0, stream>>>(x, w_qkv_w, w_o_w, xb, wqb, wob);
  gemm_bt<<<dim3(24, 32), 256, 0, stream>>>(xb, wqb, w_qkv_b, qkvb, vtb, 4096, 3072, 1024, 1024);
  attn_fwd<<<dim3(32, 32), 128, 0, stream>>>(qkvb, vtb, attnb);
  gemm_bt64<<<dim3(16, 64), 256, 0, stream>>>(attnb, wob, w_o_b, out, 4096, 1024, 1024);
}

// Round 3
// 187.029 us; speedup vs baseline: 1.0627x; 1.0627x over previous
//
#include <hip/hip_runtime.h>
#include <cstdint>
#include <cstddef>

// ---------------------------------------------------------------------------
// ChatGPTAttention: x[2,2048,1024] -> QKV proj -> causal MHA (16 heads, dk=64)
//                   -> O proj. bf16 MFMA pipeline, fp32 accumulate.
// Q pre-scaled by 1/8 in QKV-GEMM epilogue; V written transposed by the same
// epilogue (transpose_v eliminated, R14).
// LESSONS: (R5) LDS row stride multiple of 8 ushorts. (R6/R8) XOR swizzle for
// DMA-staged LDS. (R8/R9) dbuf DMA needs occupancy preserved. (R11/R15)
// direct global frags: V rows OK at 1x, K rows serialize — stage K. (R12/R13)
// 1-wave = one latency chain. (R15) split-K dead. (R16/R17 A/B) attn dur
// identical at 2 vs 4 blocks/CU. (R18 v14) split P buffers + tail reorder
// (best attn 43.2us). (R19 v15 FAILED) lag-1 PV: spills, 46.9us. (R20 v16
// FAILED) direct-global V: 16-row x 4KB-stride gather fragments each load
// into 16 transactions, latency exposed at PV; 58.4us; LDS-BW model dead
// (conflicts unchanged, time*MfmaUtil const). BOTH REVERTED -> v14 schedule.
// R21 v17: LOAD BALANCE. Round-robin dispatch (id%8->XCD, (id/8)%32->CU)
// gives CU c blocks y in {y0,y0+8,y0+16,y0+24}; qt=31-y made per-CU tile
// sums 80-4*y0 (80..52) — duration set by the 80-tile CUs (103680cyc/80 =
// 1296 cyc/tile CU throughput). New map qt = y<16 ? y : 47-y balances every
// CU to exactly 66 tiles, preserves bh->XCD locality (32y%8==0) and keeps
// each CU's biggest block among its first 3 residents (3 fit at 41.2KB).
// ---------------------------------------------------------------------------

typedef __attribute__((ext_vector_type(8))) short bf16x8;   // MFMA A/B frag
typedef __attribute__((ext_vector_type(4))) float f32x4;    // MFMA C/D frag
typedef __attribute__((ext_vector_type(4))) unsigned int u32x4;   // 16B copy
typedef __attribute__((ext_vector_type(4))) unsigned short u16x4; // 8B store
typedef __attribute__((ext_vector_type(8))) unsigned short u16x8; // 16B store

__device__ __forceinline__ unsigned short f2b(float f) {  // RNE f32->bf16
  unsigned int u = __float_as_uint(f);
  u = u + 0x7FFFu + ((u >> 16) & 1u);
  return (unsigned short)(u >> 16);
}
__device__ __forceinline__ unsigned short f2b_trunc(float f) {  // truncate
  return (unsigned short)(__float_as_uint(f) >> 16);
}

// async global->LDS DMA, 16B per lane; LDS dest = wave base + lane*16
__device__ __forceinline__ void gl_lds16(const unsigned short* g, unsigned short* s) {
  __builtin_amdgcn_global_load_lds((const __attribute__((address_space(1))) void*)g,
                                   (__attribute__((address_space(3))) void*)s, 16, 0, 0);
}

// ---------------- fp32 -> bf16, all three inputs in one launch -------------
__global__ __launch_bounds__(256) void cvt_all(const float* __restrict__ x,
                                               const float* __restrict__ wq,
                                               const float* __restrict__ wo,
                                               unsigned short* __restrict__ xb,
                                               unsigned short* __restrict__ wqb,
                                               unsigned short* __restrict__ wob) {
  const int bid = blockIdx.x;
  const float* in;
  unsigned short* out;
  int base;
  if (bid < 4096)      { in = x;  out = xb;  base = bid; }
  else if (bid < 7168) { in = wq; out = wqb; base = bid - 4096; }
  else                 { in = wo; out = wob; base = bid - 7168; }
  const int idx = (base * 256 + threadIdx.x) * 4;
  f32x4 v = *(const f32x4*)(in + idx);
  u16x4 r;
  r[0] = f2b(v[0]); r[1] = f2b(v[1]); r[2] = f2b(v[2]); r[3] = f2b(v[3]);
  *(u16x4*)(out + idx) = r;
}

// ---------------- GEMM: C[M,N] = (A[M,K] * W[N,K]^T + bias) * colscale -----
// 128x128 tile, BK=32, dbuf DMA (32KB LDS). V-column blocks (n0>=2048) write
// transposed into vt as packed u16x4. Unchanged from R14.
__global__ __launch_bounds__(256) void gemm_bt(const unsigned short* __restrict__ A,
                                               const unsigned short* __restrict__ W,
                                               const float* __restrict__ bias,
                                               unsigned short* __restrict__ Cb,
                                               unsigned short* __restrict__ vtb,
                                               int M, int N, int K, int qcols) {
  __shared__ unsigned short As[2][128 * 32];
  __shared__ unsigned short Bs[2][128 * 32];
  const int tid  = threadIdx.x;
  const int lane = tid & 63;
  const int w    = tid >> 6;
  const int wy   = w >> 1, wx = w & 1;
  const int l15  = lane & 15, quad = lane >> 4;
  const int xr2  = (l15 >> 1) & 3;
  const int m0 = blockIdx.y * 128, n0 = blockIdx.x * 128;

  const unsigned short* gA[2];
  const unsigned short* gB[2];
  int off[2];
#pragma unroll
  for (int p = 0; p < 2; ++p) {
    const int c = tid + p * 256;
    const int r = c >> 2;
    const int srcc = (c & 3) ^ ((r >> 1) & 3);
    gA[p] = A + (size_t)(m0 + r) * K + srcc * 8;
    gB[p] = W + (size_t)(n0 + r) * K + srcc * 8;
    off[p] = c * 8;
  }

  f32x4 acc[4][4];
#pragma unroll
  for (int i = 0; i < 4; ++i)
#pragma unroll
    for (int j = 0; j < 4; ++j) acc[i][j] = (f32x4){0.f, 0.f, 0.f, 0.f};

#pragma unroll
  for (int p = 0; p < 2; ++p) {
    gl_lds16(gA[p], &As[0][off[p]]);
    gl_lds16(gB[p], &Bs[0][off[p]]);
  }

  const int NIT = K >> 5;
  for (int it = 0; it < NIT; ++it) {
    __syncthreads();
    const int cur = it & 1;
    if (it + 1 < NIT) {
      const int kt = (it + 1) << 5;
#pragma unroll
      for (int p = 0; p < 2; ++p) {
        gl_lds16(gA[p] + kt, &As[cur ^ 1][off[p]]);
        gl_lds16(gB[p] + kt, &Bs[cur ^ 1][off[p]]);
      }
    }
    const unsigned short* Ac = As[cur];
    const unsigned short* Bc = Bs[cur];
    bf16x8 af[4], bfr[4];
#pragma unroll
    for (int i = 0; i < 4; ++i)
      af[i] = *(const bf16x8*)&Ac[(wy * 64 + i * 16 + l15) * 32 + (quad ^ xr2) * 8];
#pragma unroll
    for (int j = 0; j < 4; ++j)
      bfr[j] = *(const bf16x8*)&Bc[(wx * 64 + j * 16 + l15) * 32 + (quad ^ xr2) * 8];
#pragma unroll
    for (int i = 0; i < 4; ++i)
#pragma unroll
      for (int j = 0; j < 4; ++j)
        acc[i][j] = __builtin_amdgcn_mfma_f32_16x16x32_bf16(af[i], bfr[j], acc[i][j], 0, 0, 0);
  }

  const bool vblock = (n0 >= 2048);  // block-uniform
#pragma unroll
  for (int i = 0; i < 4; ++i) {
    const int row = m0 + wy * 64 + i * 16 + quad * 4;
#pragma unroll
    for (int j = 0; j < 4; ++j) {
      const int col = n0 + wx * 64 + j * 16 + l15;
      const float bv = bias[col];
      if (!vblock) {
        const float sc = (col < qcols) ? 0.125f : 1.0f;
#pragma unroll
        for (int r = 0; r < 4; ++r)
          Cb[(size_t)(row + r) * N + col] = f2b((acc[i][j][r] + bv) * sc);
      } else {
        const int hd = col - 2048;
        const int bb = row >> 11, s = row & 2047;
        u16x4 ov;
#pragma unroll
        for (int r = 0; r < 4; ++r) ov[r] = f2b(acc[i][j][r] + bv);
        *(u16x4*)(vtb + ((size_t)(bb * 1024 + hd)) * 2048 + s) = ov;
      }
    }
  }
}

// ---------------- GEMM 64x64 tile, fp32 out (O-projection) -----------------
// Grid 16x64 = 1024 blocks. BK=64 dbuf (32KB LDS, 4 blocks/CU). R17 config.
__global__ __launch_bounds__(256) void gemm_bt64(const unsigned short* __restrict__ A,
                                                 const unsigned short* __restrict__ W,
                                                 const float* __restrict__ bias,
                                                 float* __restrict__ Cf,
                                                 int M, int N, int K) {
  __shared__ unsigned short As[2][64 * 64];
  __shared__ unsigned short Bs[2][64 * 64];
  const int tid  = threadIdx.x;
  const int lane = tid & 63;
  const int w    = tid >> 6;
  const int wy   = w >> 1, wx = w & 1;
  const int l15  = lane & 15, quad = lane >> 4;
  const int xr   = l15 & 7;
  const int m0 = blockIdx.y * 64, n0 = blockIdx.x * 64;

  const unsigned short* gA[2];
  const unsigned short* gB[2];
  int off[2];
#pragma unroll
  for (int p = 0; p < 2; ++p) {
    const int c = tid + p * 256;
    const int r = c >> 3;
    const int sc = ((c & 7) ^ (r & 7)) * 8;
    gA[p] = A + (size_t)(m0 + r) * K + sc;
    gB[p] = W + (size_t)(n0 + r) * K + sc;
    off[p] = c * 8;
  }

  f32x4 acc[2][2];
#pragma unroll
  for (int i = 0; i < 2; ++i)
#pragma unroll
    for (int j = 0; j < 2; ++j) acc[i][j] = (f32x4){0.f, 0.f, 0.f, 0.f};

#pragma unroll
  for (int p = 0; p < 2; ++p) {
    gl_lds16(gA[p], &As[0][off[p]]);
    gl_lds16(gB[p], &Bs[0][off[p]]);
  }

  const int NIT = K >> 6;
  for (int it = 0; it < NIT; ++it) {
    __syncthreads();
    const int cur = it & 1;
    if (it + 1 < NIT) {
      const int kt = (it + 1) << 6;
#pragma unroll
      for (int p = 0; p < 2; ++p) {
        gl_lds16(gA[p] + kt, &As[cur ^ 1][off[p]]);
        gl_lds16(gB[p] + kt, &Bs[cur ^ 1][off[p]]);
      }
    }
    const unsigned short* Ac = As[cur];
    const unsigned short* Bc = Bs[cur];
#pragma unroll
    for (int kc = 0; kc < 2; ++kc) {
      bf16x8 af[2], bfr[2];
#pragma unroll
      for (int i = 0; i < 2; ++i)
        af[i] = *(const bf16x8*)&Ac[(wy * 32 + i * 16 + l15) * 64 + ((kc * 4 + quad) ^ xr) * 8];
#pragma unroll
      for (int j = 0; j < 2; ++j)
        bfr[j] = *(const bf16x8*)&Bc[(wx * 32 + j * 16 + l15) * 64 + ((kc * 4 + quad) ^ xr) * 8];
#pragma unroll
      for (int i = 0; i < 2; ++i)
#pragma unroll
        for (int j = 0; j < 2; ++j)
          acc[i][j] = __builtin_amdgcn_mfma_f32_16x16x32_bf16(af[i], bfr[j], acc[i][j], 0, 0, 0);
    }
  }

#pragma unroll
  for (int i = 0; i < 2; ++i) {
    const int row = m0 + wy * 32 + i * 16 + quad * 4;
#pragma unroll
    for (int j = 0; j < 2; ++j) {
      const int col = n0 + wx * 32 + j * 16 + l15;
      const float bv = bias[col];
#pragma unroll
      for (int r = 0; r < 4; ++r)
        Cf[(size_t)(row + r) * N + col] = acc[i][j][r] + bv;
    }
  }
}

// ---------------- flash attention v17: v14 + balanced qt map ---------------
// Block = 2 waves x 32 q = 64 q; grid (bh 32, qt' 32) = 1024 blocks. DMA dbuf
// XOR-swizzled K/V staging, S^T=KQ^T, O^T=V^T P^T, no-max softmax, l via
// ones-A MFMA, XCD=bh%8. v14 tail order: exp0,Pw0,exp1,Pw1,Pr0,PV0,Pr1,PV1.
// R21: qt = y<16 ? y : 47-y — every CU's 4 blocks {y0,y0+8,y0+16,y0+24} sum
// to exactly 66 tiles (was 52..80 with qt=31-y).
__global__ __launch_bounds__(128, 2) void attn_fwd(const unsigned short* __restrict__ qkv,
                                                   const unsigned short* __restrict__ vt,
                                                   unsigned short* __restrict__ o) {
  __shared__ unsigned short Ks[2][64 * 64];
  __shared__ unsigned short Vs[2][64 * 64];
  __shared__ unsigned short pbuf[2][2][16 * 72];  // [wave][subtile][16x72]
  const int tid  = threadIdx.x;
  const int lane = tid & 63;
  const int w    = tid >> 6;          // 2 waves
  const int l15  = lane & 15, quad = lane >> 4;
  const int xr   = l15 & 7;
  const int bh = blockIdx.x, b = bh >> 4, h = bh & 15;
  const int y  = (int)blockIdx.y;
  const int qt = (y < 16) ? y : 47 - y;  // per-CU balanced (66 tiles each)
  const int q0 = qt * 64;
  const int qa = q0 + w * 32;
  const int qb = qa + 16;
  const int T = qt + 1;

  // DMA staging: 512 chunks per 64x64 tile / 128 threads = 4/thread/array.
  const unsigned short* gKd[4];
  const unsigned short* gVd[4];
  int doff[4];
#pragma unroll
  for (int p = 0; p < 4; ++p) {
    const int c = tid + p * 128;
    const int r = c >> 3;
    const int sc = ((c & 7) ^ (r & 7)) * 8;
    gKd[p] = qkv + (size_t)(b * 2048 + r) * 3072 + 1024 + h * 64 + sc;
    gVd[p] = vt + (size_t)(bh * 64 + r) * 2048 + sc;
    doff[p] = c * 8;
  }

  const unsigned short* qra = qkv + (size_t)(b * 2048 + qa + l15) * 3072 + h * 64;
  const unsigned short* qrb = qkv + (size_t)(b * 2048 + qb + l15) * 3072 + h * 64;
  const bf16x8 bq[2][2] = {
    { *(const bf16x8*)(qra + quad * 8), *(const bf16x8*)(qra + 32 + quad * 8) },
    { *(const bf16x8*)(qrb + quad * 8), *(const bf16x8*)(qrb + 32 + quad * 8) } };

  bf16x8 vones;
#pragma unroll
  for (int k = 0; k < 8; ++k) vones[k] = (short)0x3F80;  // bf16 1.0

  f32x4 acc[2][4];   // [q-subtile][d-tile] — O^T C-layout: col=q(l15), row=d
#pragma unroll
  for (int i = 0; i < 2; ++i)
#pragma unroll
    for (int j = 0; j < 4; ++j) acc[i][j] = (f32x4){0.f, 0.f, 0.f, 0.f};
  f32x4 accL[2] = {(f32x4){0.f, 0.f, 0.f, 0.f}, (f32x4){0.f, 0.f, 0.f, 0.f}};

  unsigned short* P0 = pbuf[w][0];
  unsigned short* P1 = pbuf[w][1];

  // prologue: DMA tile 0 -> buf 0
#pragma unroll
  for (int p = 0; p < 4; ++p) {
    gl_lds16(gKd[p], &Ks[0][doff[p]]);
    gl_lds16(gVd[p], &Vs[0][doff[p]]);
  }

  for (int t = 0; t < T; ++t) {
    __syncthreads();  // drains DMA for buf(t&1); other buf's reads done
    const int cur = t & 1;
    if (t + 1 < T) {
      const size_t ko = (size_t)(t + 1) * 64 * 3072;
      const int vo = (t + 1) * 64;
#pragma unroll
      for (int p = 0; p < 4; ++p) {
        gl_lds16(gKd[p] + ko, &Ks[cur ^ 1][doff[p]]);
        gl_lds16(gVd[p] + vo, &Vs[cur ^ 1][doff[p]]);
      }
    }
    const unsigned short* Kc = Ks[cur];
    const unsigned short* Vc = Vs[cur];
    const int kv0 = t * 64;

    // ---- S^T[kv][q] = K Q^T for both q-subtiles (K frags swizzled) ----
    f32x4 st[2][4];
#pragma unroll
    for (int n = 0; n < 4; ++n) {
      const int row = n * 16 + l15;
      const bf16x8 kA0 = *(const bf16x8*)&Kc[row * 64 + ((quad) ^ xr) * 8];
      const bf16x8 kA1 = *(const bf16x8*)&Kc[row * 64 + ((4 + quad) ^ xr) * 8];
      f32x4 z0 = (f32x4){0.f, 0.f, 0.f, 0.f};
      z0 = __builtin_amdgcn_mfma_f32_16x16x32_bf16(kA0, bq[0][0], z0, 0, 0, 0);
      z0 = __builtin_amdgcn_mfma_f32_16x16x32_bf16(kA1, bq[0][1], z0, 0, 0, 0);
      st[0][n] = z0;
      f32x4 z1 = (f32x4){0.f, 0.f, 0.f, 0.f};
      z1 = __builtin_amdgcn_mfma_f32_16x16x32_bf16(kA0, bq[1][0], z1, 0, 0, 0);
      z1 = __builtin_amdgcn_mfma_f32_16x16x32_bf16(kA1, bq[1][1], z1, 0, 0, 0);
      st[1][n] = z1;
    }
    // ---- V^T A-frags (swizzled LDS reads, shared by both subtiles) ----
    bf16x8 av[4][2];
#pragma unroll
    for (int j = 0; j < 4; ++j) {
      const int row = j * 16 + l15;
      av[j][0] = *(const bf16x8*)&Vc[row * 64 + ((quad) ^ xr) * 8];
      av[j][1] = *(const bf16x8*)&Vc[row * 64 + ((4 + quad) ^ xr) * 8];
    }
    // ---- mask/exp + P writes for BOTH subtiles (separate buffers) ----
#pragma unroll
    for (int tq = 0; tq < 2; ++tq) {
      unsigned short* P = tq ? P1 : P0;
      const int qbase = tq ? qb : qa;
      if (kv0 + 63 > qbase) {
        const int qrow = qbase + l15;
#pragma unroll
        for (int n = 0; n < 4; ++n)
#pragma unroll
          for (int r = 0; r < 4; ++r)
            if (kv0 + n * 16 + quad * 4 + r > qrow) st[tq][n][r] = -1e30f;
      }
#pragma unroll
      for (int n = 0; n < 4; ++n) {
#pragma unroll
        for (int r = 0; r < 4; ++r) st[tq][n][r] = __expf(st[tq][n][r]);
        u16x4 pw;
        pw[0] = f2b_trunc(st[tq][n][0]); pw[1] = f2b_trunc(st[tq][n][1]);
        pw[2] = f2b_trunc(st[tq][n][2]); pw[3] = f2b_trunc(st[tq][n][3]);
        *(u16x4*)&P[l15 * 72 + n * 16 + quad * 4] = pw;
      }
    }
    // ---- PV for both subtiles (reads pipeline behind the writes) ----
#pragma unroll
    for (int tq = 0; tq < 2; ++tq) {
      const unsigned short* P = tq ? P1 : P0;
      const bf16x8 bp0 = *(const bf16x8*)&P[l15 * 72 + quad * 8];
      const bf16x8 bp1 = *(const bf16x8*)&P[l15 * 72 + 32 + quad * 8];
      accL[tq] = __builtin_amdgcn_mfma_f32_16x16x32_bf16(vones, bp0, accL[tq], 0, 0, 0);
      accL[tq] = __builtin_amdgcn_mfma_f32_16x16x32_bf16(vones, bp1, accL[tq], 0, 0, 0);
#pragma unroll
      for (int j = 0; j < 4; ++j) {
        acc[tq][j] = __builtin_amdgcn_mfma_f32_16x16x32_bf16(av[j][0], bp0, acc[tq][j], 0, 0, 0);
        acc[tq][j] = __builtin_amdgcn_mfma_f32_16x16x32_bf16(av[j][1], bp1, acc[tq][j], 0, 0, 0);
      }
    }
  }
  // ---- epilogue: lane holds q=l15, d=j*16+quad*4+r -> packed u16x4 ----
#pragma unroll
  for (int tq = 0; tq < 2; ++tq) {
    const int qrow = (tq ? qb : qa) + l15;
    const float inv = 1.0f / accL[tq][0];  // all rows of accL equal l[q]
    unsigned short* orow = o + (size_t)(b * 2048 + qrow) * 1024 + h * 64;
#pragma unroll
    for (int j = 0; j < 4; ++j) {
      u16x4 ov;
      ov[0] = f2b(acc[tq][j][0] * inv); ov[1] = f2b(acc[tq][j][1] * inv);
      ov[2] = f2b(acc[tq][j][2] * inv); ov[3] = f2b(acc[tq][j][3] * inv);
      *(u16x4*)(orow + j * 16 + quad * 4) = ov;
    }
  }
}

// ---------------------------------------------------------------------------
extern "C" void kernel_launch(void* const* d_in, const int* in_sizes, int n_in,
                              void* d_out, int out_size, void* d_ws, size_t ws_size,
                              hipStream_t stream) {
  const float* x       = (const float*)d_in[0];
  // d_in[1] = mask: causal tril by construction; implemented analytically.
  const float* w_qkv_w = (const float*)d_in[2];
  const float* w_qkv_b = (const float*)d_in[3];
  const float* w_o_w   = (const float*)d_in[4];
  const float* w_o_b   = (const float*)d_in[5];
  float* out = (float*)d_out;

  unsigned short* ws    = (unsigned short*)d_ws;
  unsigned short* xb    = ws;                                  // 4096*1024
  unsigned short* wqb   = xb   + (size_t)4096 * 1024;          // 3072*1024
  unsigned short* wob   = wqb  + (size_t)3072 * 1024;          // 1024*1024
  unsigned short* qkvb  = wob  + (size_t)1024 * 1024;          // 4096*3072
  unsigned short* vtb   = qkvb + (size_t)4096 * 3072;          // 2048*2048
  unsigned short* attnb = vtb  + (size_t)2048 * 2048;          // 4096*1024

  cvt_all<<<8192, 256, 0, stream>>>(x, w_qkv_w, w_o_w, xb, wqb, wob);
  gemm_bt<<<dim3(24, 32), 256, 0, stream>>>(xb, wqb, w_qkv_b, qkvb, vtb, 4096, 3072, 1024, 1024);
  attn_fwd<<<dim3(32, 32), 128, 0, stream>>>(qkvb, vtb, attnb);
  gemm_bt64<<<dim3(16, 64), 256, 0, stream>>>(attnb, wob, w_o_b, out, 4096, 1024, 1024);
}

// Round 5
// 179.207 us; speedup vs baseline: 1.1091x; 1.0436x over previous
//
#include <hip/hip_runtime.h>
#include <cstdint>
#include <cstddef>

// ---------------------------------------------------------------------------
// ChatGPTAttention: x[2,2048,1024] -> QKV proj -> causal MHA (16 heads, dk=64)
//                   -> O proj. bf16 MFMA pipeline, fp32 accumulate.
// Q pre-scaled by 1/8 in QKV-GEMM epilogue; V written transposed by the same
// epilogue (R14).
// LESSONS: (R5) LDS row stride multiple of 8 ushorts. (R6/R8) XOR swizzle for
// DMA-staged LDS. (R11/R15) direct global frags: K/V-row gathers fragment.
// (R18 v14) split P buffers + tail reorder; attn 43.2us. (R19 FAILED) lag-1
// PV: spills. (R20 FAILED) direct-global V: latency exposed, 58us. (R21 NULL)
// per-CU tile balancing: 44.5us — per-CU throughput does NOT set duration.
// SURVIVING MODEL: makespan = longest block's serial chain. 103,680cyc/32
// tiles = 3,240 cyc/tile per-block latency; MFMA busy 7.3us + VALU 11.6us
// << 43us -> all waves stalled together; 6 waves/CU too few chains.
// R22 v18 (RESUBMIT — R4 bench was GPUAcquisitionTimeout, never ran):
// 4-WAVE q x kv SPLIT. Wave (wq,wk) does q-half wq x kv-half wk:
// 8 S^T MFMA, 16 exp/lane, 4+4 frags, 1 P-read, 10 PV MFMA (all ~halved per
// wave; per-block LDS traffic UNCHANGED). Waves/CU 6->12. Cross-wave kv-half
// combine (acc,l) once per block in the dead K/V buffers. P stride 40 (80B,
// 2-way bank pattern = free per m136). LDS 42KB -> 3 blocks/CU.
// ---------------------------------------------------------------------------

typedef __attribute__((ext_vector_type(8))) short bf16x8;   // MFMA A/B frag
typedef __attribute__((ext_vector_type(4))) float f32x4;    // MFMA C/D frag
typedef __attribute__((ext_vector_type(4))) unsigned int u32x4;   // 16B copy
typedef __attribute__((ext_vector_type(4))) unsigned short u16x4; // 8B store
typedef __attribute__((ext_vector_type(8))) unsigned short u16x8; // 16B store

__device__ __forceinline__ unsigned short f2b(float f) {  // RNE f32->bf16
  unsigned int u = __float_as_uint(f);
  u = u + 0x7FFFu + ((u >> 16) & 1u);
  return (unsigned short)(u >> 16);
}
__device__ __forceinline__ unsigned short f2b_trunc(float f) {  // truncate
  return (unsigned short)(__float_as_uint(f) >> 16);
}

// async global->LDS DMA, 16B per lane; LDS dest = wave base + lane*16
__device__ __forceinline__ void gl_lds16(const unsigned short* g, unsigned short* s) {
  __builtin_amdgcn_global_load_lds((const __attribute__((address_space(1))) void*)g,
                                   (__attribute__((address_space(3))) void*)s, 16, 0, 0);
}

// ---------------- fp32 -> bf16, all three inputs in one launch -------------
__global__ __launch_bounds__(256) void cvt_all(const float* __restrict__ x,
                                               const float* __restrict__ wq,
                                               const float* __restrict__ wo,
                                               unsigned short* __restrict__ xb,
                                               unsigned short* __restrict__ wqb,
                                               unsigned short* __restrict__ wob) {
  const int bid = blockIdx.x;
  const float* in;
  unsigned short* out;
  int base;
  if (bid < 4096)      { in = x;  out = xb;  base = bid; }
  else if (bid < 7168) { in = wq; out = wqb; base = bid - 4096; }
  else                 { in = wo; out = wob; base = bid - 7168; }
  const int idx = (base * 256 + threadIdx.x) * 4;
  f32x4 v = *(const f32x4*)(in + idx);
  u16x4 r;
  r[0] = f2b(v[0]); r[1] = f2b(v[1]); r[2] = f2b(v[2]); r[3] = f2b(v[3]);
  *(u16x4*)(out + idx) = r;
}

// ---------------- GEMM: C[M,N] = (A[M,K] * W[N,K]^T + bias) * colscale -----
// 128x128 tile, BK=32, dbuf DMA (32KB LDS). V-column blocks (n0>=2048) write
// transposed into vt as packed u16x4. Unchanged from R14.
__global__ __launch_bounds__(256) void gemm_bt(const unsigned short* __restrict__ A,
                                               const unsigned short* __restrict__ W,
                                               const float* __restrict__ bias,
                                               unsigned short* __restrict__ Cb,
                                               unsigned short* __restrict__ vtb,
                                               int M, int N, int K, int qcols) {
  __shared__ unsigned short As[2][128 * 32];
  __shared__ unsigned short Bs[2][128 * 32];
  const int tid  = threadIdx.x;
  const int lane = tid & 63;
  const int w    = tid >> 6;
  const int wy   = w >> 1, wx = w & 1;
  const int l15  = lane & 15, quad = lane >> 4;
  const int xr2  = (l15 >> 1) & 3;
  const int m0 = blockIdx.y * 128, n0 = blockIdx.x * 128;

  const unsigned short* gA[2];
  const unsigned short* gB[2];
  int off[2];
#pragma unroll
  for (int p = 0; p < 2; ++p) {
    const int c = tid + p * 256;
    const int r = c >> 2;
    const int srcc = (c & 3) ^ ((r >> 1) & 3);
    gA[p] = A + (size_t)(m0 + r) * K + srcc * 8;
    gB[p] = W + (size_t)(n0 + r) * K + srcc * 8;
    off[p] = c * 8;
  }

  f32x4 acc[4][4];
#pragma unroll
  for (int i = 0; i < 4; ++i)
#pragma unroll
    for (int j = 0; j < 4; ++j) acc[i][j] = (f32x4){0.f, 0.f, 0.f, 0.f};

#pragma unroll
  for (int p = 0; p < 2; ++p) {
    gl_lds16(gA[p], &As[0][off[p]]);
    gl_lds16(gB[p], &Bs[0][off[p]]);
  }

  const int NIT = K >> 5;
  for (int it = 0; it < NIT; ++it) {
    __syncthreads();
    const int cur = it & 1;
    if (it + 1 < NIT) {
      const int kt = (it + 1) << 5;
#pragma unroll
      for (int p = 0; p < 2; ++p) {
        gl_lds16(gA[p] + kt, &As[cur ^ 1][off[p]]);
        gl_lds16(gB[p] + kt, &Bs[cur ^ 1][off[p]]);
      }
    }
    const unsigned short* Ac = As[cur];
    const unsigned short* Bc = Bs[cur];
    bf16x8 af[4], bfr[4];
#pragma unroll
    for (int i = 0; i < 4; ++i)
      af[i] = *(const bf16x8*)&Ac[(wy * 64 + i * 16 + l15) * 32 + (quad ^ xr2) * 8];
#pragma unroll
    for (int j = 0; j < 4; ++j)
      bfr[j] = *(const bf16x8*)&Bc[(wx * 64 + j * 16 + l15) * 32 + (quad ^ xr2) * 8];
#pragma unroll
    for (int i = 0; i < 4; ++i)
#pragma unroll
      for (int j = 0; j < 4; ++j)
        acc[i][j] = __builtin_amdgcn_mfma_f32_16x16x32_bf16(af[i], bfr[j], acc[i][j], 0, 0, 0);
  }

  const bool vblock = (n0 >= 2048);  // block-uniform
#pragma unroll
  for (int i = 0; i < 4; ++i) {
    const int row = m0 + wy * 64 + i * 16 + quad * 4;
#pragma unroll
    for (int j = 0; j < 4; ++j) {
      const int col = n0 + wx * 64 + j * 16 + l15;
      const float bv = bias[col];
      if (!vblock) {
        const float sc = (col < qcols) ? 0.125f : 1.0f;
#pragma unroll
        for (int r = 0; r < 4; ++r)
          Cb[(size_t)(row + r) * N + col] = f2b((acc[i][j][r] + bv) * sc);
      } else {
        const int hd = col - 2048;
        const int bb = row >> 11, s = row & 2047;
        u16x4 ov;
#pragma unroll
        for (int r = 0; r < 4; ++r) ov[r] = f2b(acc[i][j][r] + bv);
        *(u16x4*)(vtb + ((size_t)(bb * 1024 + hd)) * 2048 + s) = ov;
      }
    }
  }
}

// ---------------- GEMM 64x64 tile, fp32 out (O-projection) -----------------
// Grid 16x64 = 1024 blocks. BK=64 dbuf (32KB LDS, 4 blocks/CU). R17 config.
__global__ __launch_bounds__(256) void gemm_bt64(const unsigned short* __restrict__ A,
                                                 const unsigned short* __restrict__ W,
                                                 const float* __restrict__ bias,
                                                 float* __restrict__ Cf,
                                                 int M, int N, int K) {
  __shared__ unsigned short As[2][64 * 64];
  __shared__ unsigned short Bs[2][64 * 64];
  const int tid  = threadIdx.x;
  const int lane = tid & 63;
  const int w    = tid >> 6;
  const int wy   = w >> 1, wx = w & 1;
  const int l15  = lane & 15, quad = lane >> 4;
  const int xr   = l15 & 7;
  const int m0 = blockIdx.y * 64, n0 = blockIdx.x * 64;

  const unsigned short* gA[2];
  const unsigned short* gB[2];
  int off[2];
#pragma unroll
  for (int p = 0; p < 2; ++p) {
    const int c = tid + p * 256;
    const int r = c >> 3;
    const int sc = ((c & 7) ^ (r & 7)) * 8;
    gA[p] = A + (size_t)(m0 + r) * K + sc;
    gB[p] = W + (size_t)(n0 + r) * K + sc;
    off[p] = c * 8;
  }

  f32x4 acc[2][2];
#pragma unroll
  for (int i = 0; i < 2; ++i)
#pragma unroll
    for (int j = 0; j < 2; ++j) acc[i][j] = (f32x4){0.f, 0.f, 0.f, 0.f};

#pragma unroll
  for (int p = 0; p < 2; ++p) {
    gl_lds16(gA[p], &As[0][off[p]]);
    gl_lds16(gB[p], &Bs[0][off[p]]);
  }

  const int NIT = K >> 6;
  for (int it = 0; it < NIT; ++it) {
    __syncthreads();
    const int cur = it & 1;
    if (it + 1 < NIT) {
      const int kt = (it + 1) << 6;
#pragma unroll
      for (int p = 0; p < 2; ++p) {
        gl_lds16(gA[p] + kt, &As[cur ^ 1][off[p]]);
        gl_lds16(gB[p] + kt, &Bs[cur ^ 1][off[p]]);
      }
    }
    const unsigned short* Ac = As[cur];
    const unsigned short* Bc = Bs[cur];
#pragma unroll
    for (int kc = 0; kc < 2; ++kc) {
      bf16x8 af[2], bfr[2];
#pragma unroll
      for (int i = 0; i < 2; ++i)
        af[i] = *(const bf16x8*)&Ac[(wy * 32 + i * 16 + l15) * 64 + ((kc * 4 + quad) ^ xr) * 8];
#pragma unroll
      for (int j = 0; j < 2; ++j)
        bfr[j] = *(const bf16x8*)&Bc[(wx * 32 + j * 16 + l15) * 64 + ((kc * 4 + quad) ^ xr) * 8];
#pragma unroll
      for (int i = 0; i < 2; ++i)
#pragma unroll
        for (int j = 0; j < 2; ++j)
          acc[i][j] = __builtin_amdgcn_mfma_f32_16x16x32_bf16(af[i], bfr[j], acc[i][j], 0, 0, 0);
    }
  }

#pragma unroll
  for (int i = 0; i < 2; ++i) {
    const int row = m0 + wy * 32 + i * 16 + quad * 4;
#pragma unroll
    for (int j = 0; j < 2; ++j) {
      const int col = n0 + wx * 32 + j * 16 + l15;
      const float bv = bias[col];
#pragma unroll
      for (int r = 0; r < 4; ++r)
        Cf[(size_t)(row + r) * N + col] = acc[i][j][r] + bv;
    }
  }
}

// ---------------- flash attention v18: 4-wave q x kv split -----------------
// Block = 4 waves (wq,wk in 2x2), 64 q x 64 kv tiles; grid (bh 32, y 32).
// Wave (wq,wk): q-half wq (2 subtiles of 16) x kv-half wk (32 kv). Per wave
// per tile: 4 K-frags, 8 S^T MFMA, 16 exp, 4 Pw, 1 Pr + 4 V-frags, 10 PV
// MFMA — per-block LDS traffic unchanged vs v14, per-wave chain ~halved,
// 12 waves/CU. kv-half partials (acc, accL) combined once per block via the
// dead K/V LDS buffers. qt map y<16?y:47-y (R21, neutral). XCD=bh%8.
__global__ __launch_bounds__(256, 3) void attn_fwd(const unsigned short* __restrict__ qkv,
                                                   const unsigned short* __restrict__ vt,
                                                   unsigned short* __restrict__ o) {
  __shared__ unsigned short Ks[2][64 * 64];
  __shared__ unsigned short Vs[2][64 * 64];
  __shared__ unsigned short pbuf[4][2][16 * 40];  // [wave][subtile][16 x (32+8)]
  const int tid  = threadIdx.x;
  const int lane = tid & 63;
  const int w    = tid >> 6;          // 4 waves
  const int wq   = w & 1;             // q-half (32 q)
  const int wk   = w >> 1;            // kv-half (32 kv)
  const int l15  = lane & 15, quad = lane >> 4;
  const int xr   = l15 & 7;
  const int bh = blockIdx.x, b = bh >> 4, h = bh & 15;
  const int y  = (int)blockIdx.y;
  const int qt = (y < 16) ? y : 47 - y;  // per-CU balanced (R21)
  const int q0 = qt * 64;
  const int T = qt + 1;
  const int qs0 = q0 + wq * 32;       // subtile 0 base
  const int qs1 = qs0 + 16;           // subtile 1 base

  // DMA staging: 512 chunks per 64x64 tile / 256 threads = 2/thread/array.
  const unsigned short* gKd[2];
  const unsigned short* gVd[2];
  int doff[2];
#pragma unroll
  for (int p = 0; p < 2; ++p) {
    const int c = tid + p * 256;
    const int r = c >> 3;
    const int sc = ((c & 7) ^ (r & 7)) * 8;
    gKd[p] = qkv + (size_t)(b * 2048 + r) * 3072 + 1024 + h * 64 + sc;
    gVd[p] = vt + (size_t)(bh * 64 + r) * 2048 + sc;
    doff[p] = c * 8;
  }

  const unsigned short* qr0 = qkv + (size_t)(b * 2048 + qs0 + l15) * 3072 + h * 64;
  const unsigned short* qr1 = qkv + (size_t)(b * 2048 + qs1 + l15) * 3072 + h * 64;
  const bf16x8 bq[2][2] = {
    { *(const bf16x8*)(qr0 + quad * 8), *(const bf16x8*)(qr0 + 32 + quad * 8) },
    { *(const bf16x8*)(qr1 + quad * 8), *(const bf16x8*)(qr1 + 32 + quad * 8) } };

  bf16x8 vones;
#pragma unroll
  for (int k = 0; k < 8; ++k) vones[k] = (short)0x3F80;  // bf16 1.0

  f32x4 acc[2][4];   // [subtile][d-tile], PARTIAL over this wave's kv-half
#pragma unroll
  for (int i = 0; i < 2; ++i)
#pragma unroll
    for (int j = 0; j < 4; ++j) acc[i][j] = (f32x4){0.f, 0.f, 0.f, 0.f};
  f32x4 accL[2] = {(f32x4){0.f, 0.f, 0.f, 0.f}, (f32x4){0.f, 0.f, 0.f, 0.f}};

  unsigned short* P0 = pbuf[w][0];
  unsigned short* P1 = pbuf[w][1];

  // prologue: DMA tile 0 -> buf 0
#pragma unroll
  for (int p = 0; p < 2; ++p) {
    gl_lds16(gKd[p], &Ks[0][doff[p]]);
    gl_lds16(gVd[p], &Vs[0][doff[p]]);
  }

  for (int t = 0; t < T; ++t) {
    __syncthreads();  // drains DMA for buf(t&1)
    const int cur = t & 1;
    if (t + 1 < T) {
      const size_t ko = (size_t)(t + 1) * 64 * 3072;
      const int vo = (t + 1) * 64;
#pragma unroll
      for (int p = 0; p < 2; ++p) {
        gl_lds16(gKd[p] + ko, &Ks[cur ^ 1][doff[p]]);
        gl_lds16(gVd[p] + vo, &Vs[cur ^ 1][doff[p]]);
      }
    }
    const unsigned short* Kc = Ks[cur];
    const unsigned short* Vc = Vs[cur];
    const int kv0 = t * 64 + wk * 32;   // this wave's kv base

    // ---- S^T[kv][q] = K Q^T, this wave's 32 kv x 32 q ----
    bf16x8 kA[2][2];
#pragma unroll
    for (int n = 0; n < 2; ++n) {
      const int row = wk * 32 + n * 16 + l15;
      kA[n][0] = *(const bf16x8*)&Kc[row * 64 + ((quad) ^ xr) * 8];
      kA[n][1] = *(const bf16x8*)&Kc[row * 64 + ((4 + quad) ^ xr) * 8];
    }
    f32x4 st[2][2];
#pragma unroll
    for (int s = 0; s < 2; ++s)
#pragma unroll
      for (int n = 0; n < 2; ++n) {
        f32x4 z = (f32x4){0.f, 0.f, 0.f, 0.f};
        z = __builtin_amdgcn_mfma_f32_16x16x32_bf16(kA[n][0], bq[s][0], z, 0, 0, 0);
        z = __builtin_amdgcn_mfma_f32_16x16x32_bf16(kA[n][1], bq[s][1], z, 0, 0, 0);
        st[s][n] = z;
      }
    // ---- V^T A-frags for this kv-half ----
    bf16x8 av[4];
#pragma unroll
    for (int j = 0; j < 4; ++j) {
      const int row = j * 16 + l15;
      av[j] = *(const bf16x8*)&Vc[row * 64 + ((wk * 4 + quad) ^ xr) * 8];
    }
    // ---- mask/exp + P writes for both subtiles ----
#pragma unroll
    for (int s = 0; s < 2; ++s) {
      unsigned short* P = s ? P1 : P0;
      const int qbase = s ? qs1 : qs0;
      if (kv0 + 31 > qbase) {
        const int qrow = qbase + l15;
#pragma unroll
        for (int n = 0; n < 2; ++n)
#pragma unroll
          for (int r = 0; r < 4; ++r)
            if (kv0 + n * 16 + quad * 4 + r > qrow) st[s][n][r] = -1e30f;
      }
#pragma unroll
      for (int n = 0; n < 2; ++n) {
#pragma unroll
        for (int r = 0; r < 4; ++r) st[s][n][r] = __expf(st[s][n][r]);
        u16x4 pw;
        pw[0] = f2b_trunc(st[s][n][0]); pw[1] = f2b_trunc(st[s][n][1]);
        pw[2] = f2b_trunc(st[s][n][2]); pw[3] = f2b_trunc(st[s][n][3]);
        *(u16x4*)&P[l15 * 40 + n * 16 + quad * 4] = pw;
      }
    }
    // ---- Pr + PV (K=32 contraction = exactly one MFMA per (s,j)) ----
#pragma unroll
    for (int s = 0; s < 2; ++s) {
      const unsigned short* P = s ? P1 : P0;
      const bf16x8 bp = *(const bf16x8*)&P[l15 * 40 + quad * 8];
      accL[s] = __builtin_amdgcn_mfma_f32_16x16x32_bf16(vones, bp, accL[s], 0, 0, 0);
#pragma unroll
      for (int j = 0; j < 4; ++j)
        acc[s][j] = __builtin_amdgcn_mfma_f32_16x16x32_bf16(av[j], bp, acc[s][j], 0, 0, 0);
    }
  }

  // ---- cross-wave kv-half combine (once per block; K/V buffers are dead) --
  __syncthreads();
  float* cmbA = (float*)&Ks[0][0];   // 16 frags x 256 floats = 16KB = Ks
  float* cmbL = (float*)&Vs[0][0];   // 4 x 64 floats = 1KB
  if (wk == 1) {
#pragma unroll
    for (int s = 0; s < 2; ++s) {
      cmbL[(wq * 2 + s) * 64 + lane] = accL[s][0];
#pragma unroll
      for (int j = 0; j < 4; ++j)
        *(f32x4*)&cmbA[(((wq * 2 + s) * 4 + j) << 8) + lane * 4] = acc[s][j];
    }
  }
  __syncthreads();
  if (wk == 0) {
#pragma unroll
    for (int s = 0; s < 2; ++s) {
      const float lsum = accL[s][0] + cmbL[(wq * 2 + s) * 64 + lane];
      const float inv = 1.0f / lsum;
      const int qrow = (s ? qs1 : qs0) + l15;
      unsigned short* orow = o + (size_t)(b * 2048 + qrow) * 1024 + h * 64;
#pragma unroll
      for (int j = 0; j < 4; ++j) {
        const f32x4 oth = *(const f32x4*)&cmbA[(((wq * 2 + s) * 4 + j) << 8) + lane * 4];
        u16x4 ov;
        ov[0] = f2b((acc[s][j][0] + oth[0]) * inv);
        ov[1] = f2b((acc[s][j][1] + oth[1]) * inv);
        ov[2] = f2b((acc[s][j][2] + oth[2]) * inv);
        ov[3] = f2b((acc[s][j][3] + oth[3]) * inv);
        *(u16x4*)(orow + j * 16 + quad * 4) = ov;
      }
    }
  }
}

// ---------------------------------------------------------------------------
extern "C" void kernel_launch(void* const* d_in, const int* in_sizes, int n_in,
                              void* d_out, int out_size, void* d_ws, size_t ws_size,
                              hipStream_t stream) {
  const float* x       = (const float*)d_in[0];
  // d_in[1] = mask: causal tril by construction; implemented analytically.
  const float* w_qkv_w = (const float*)d_in[2];
  const float* w_qkv_b = (const float*)d_in[3];
  const float* w_o_w   = (const float*)d_in[4];
  const float* w_o_b   = (const float*)d_in[5];
  float* out = (float*)d_out;

  unsigned short* ws    = (unsigned short*)d_ws;
  unsigned short* xb    = ws;                                  // 4096*1024
  unsigned short* wqb   = xb   + (size_t)4096 * 1024;          // 3072*1024
  unsigned short* wob   = wqb  + (size_t)3072 * 1024;          // 1024*1024
  unsigned short* qkvb  = wob  + (size_t)1024 * 1024;          // 4096*3072
  unsigned short* vtb   = qkvb + (size_t)4096 * 3072;          // 2048*2048
  unsigned short* attnb = vtb  + (size_t)2048 * 2048;          // 4096*1024

  cvt_all<<<8192, 256, 0, stream>>>(x, w_qkv_w, w_o_w, xb, wqb, wob);
  gemm_bt<<<dim3(24, 32), 256, 0, stream>>>(xb, wqb, w_qkv_b, qkvb, vtb, 4096, 3072, 1024, 1024);
  attn_fwd<<<dim3(32, 32), 256, 0, stream>>>(qkvb, vtb, attnb);
  gemm_bt64<<<dim3(16, 64), 256, 0, stream>>>(attnb, wob, w_o_b, out, 4096, 1024, 1024);
}

// Round 6
// 179.087 us; speedup vs baseline: 1.1099x; 1.0007x over previous
//
#include <hip/hip_runtime.h>
#include <cstdint>
#include <cstddef>

// ---------------------------------------------------------------------------
// ChatGPTAttention: x[2,2048,1024] -> QKV proj -> causal MHA (16 heads, dk=64)
//                   -> O proj. bf16 MFMA pipeline, fp32 accumulate.
// Q pre-scaled by 1/8 in QKV-GEMM epilogue; V written transposed by the same
// epilogue (R14).
// LESSONS: (R5) LDS row stride multiple of 8 ushorts. (R6/R8) XOR swizzle for
// DMA-staged LDS. (R11/R15) direct global frags: K/V-row gathers fragment.
// (R18 v14) split P buffers; attn 43.2us. (R19 FAILED) lag-1 PV: spills.
// (R20 FAILED) direct-global V: 58us. (R21 NULL) per-CU tile balancing.
// (R22 v18 WIN) 4-wave q x kv split: total 187.0->179.2; attn now <41.4us
// (below the harness fill kernels in top-5) — chain model right, ~60% of
// predicted gain; remainder is per-tile barrier+DMA-drain fixed cost.
// R23: GEMM phase now dominates (~40us gemm_bt + ~25us gemm_bt64 est.).
// gemm_bt64 was a 64x64 tile = the measured 343-TF ladder point (8 MFMA :
// 8 frag reads per iter). Retile to 128x64 (BM=128,BN=64,BK=64): 16 MFMA :
// 12 frag reads, same XOR swizzle (row stride still 64 ushorts), LDS 48KB,
// grid (16,32)=512 blocks = 2/CU. Expected ~600TF -> ~14us.
// ---------------------------------------------------------------------------

typedef __attribute__((ext_vector_type(8))) short bf16x8;   // MFMA A/B frag
typedef __attribute__((ext_vector_type(4))) float f32x4;    // MFMA C/D frag
typedef __attribute__((ext_vector_type(4))) unsigned int u32x4;   // 16B copy
typedef __attribute__((ext_vector_type(4))) unsigned short u16x4; // 8B store
typedef __attribute__((ext_vector_type(8))) unsigned short u16x8; // 16B store

__device__ __forceinline__ unsigned short f2b(float f) {  // RNE f32->bf16
  unsigned int u = __float_as_uint(f);
  u = u + 0x7FFFu + ((u >> 16) & 1u);
  return (unsigned short)(u >> 16);
}
__device__ __forceinline__ unsigned short f2b_trunc(float f) {  // truncate
  return (unsigned short)(__float_as_uint(f) >> 16);
}

// async global->LDS DMA, 16B per lane; LDS dest = wave base + lane*16
__device__ __forceinline__ void gl_lds16(const unsigned short* g, unsigned short* s) {
  __builtin_amdgcn_global_load_lds((const __attribute__((address_space(1))) void*)g,
                                   (__attribute__((address_space(3))) void*)s, 16, 0, 0);
}

// ---------------- fp32 -> bf16, all three inputs in one launch -------------
__global__ __launch_bounds__(256) void cvt_all(const float* __restrict__ x,
                                               const float* __restrict__ wq,
                                               const float* __restrict__ wo,
                                               unsigned short* __restrict__ xb,
                                               unsigned short* __restrict__ wqb,
                                               unsigned short* __restrict__ wob) {
  const int bid = blockIdx.x;
  const float* in;
  unsigned short* out;
  int base;
  if (bid < 4096)      { in = x;  out = xb;  base = bid; }
  else if (bid < 7168) { in = wq; out = wqb; base = bid - 4096; }
  else                 { in = wo; out = wob; base = bid - 7168; }
  const int idx = (base * 256 + threadIdx.x) * 4;
  f32x4 v = *(const f32x4*)(in + idx);
  u16x4 r;
  r[0] = f2b(v[0]); r[1] = f2b(v[1]); r[2] = f2b(v[2]); r[3] = f2b(v[3]);
  *(u16x4*)(out + idx) = r;
}

// ---------------- GEMM: C[M,N] = (A[M,K] * W[N,K]^T + bias) * colscale -----
// 128x128 tile, BK=32, dbuf DMA (32KB LDS). V-column blocks (n0>=2048) write
// transposed into vt as packed u16x4. Unchanged from R14.
__global__ __launch_bounds__(256) void gemm_bt(const unsigned short* __restrict__ A,
                                               const unsigned short* __restrict__ W,
                                               const float* __restrict__ bias,
                                               unsigned short* __restrict__ Cb,
                                               unsigned short* __restrict__ vtb,
                                               int M, int N, int K, int qcols) {
  __shared__ unsigned short As[2][128 * 32];
  __shared__ unsigned short Bs[2][128 * 32];
  const int tid  = threadIdx.x;
  const int lane = tid & 63;
  const int w    = tid >> 6;
  const int wy   = w >> 1, wx = w & 1;
  const int l15  = lane & 15, quad = lane >> 4;
  const int xr2  = (l15 >> 1) & 3;
  const int m0 = blockIdx.y * 128, n0 = blockIdx.x * 128;

  const unsigned short* gA[2];
  const unsigned short* gB[2];
  int off[2];
#pragma unroll
  for (int p = 0; p < 2; ++p) {
    const int c = tid + p * 256;
    const int r = c >> 2;
    const int srcc = (c & 3) ^ ((r >> 1) & 3);
    gA[p] = A + (size_t)(m0 + r) * K + srcc * 8;
    gB[p] = W + (size_t)(n0 + r) * K + srcc * 8;
    off[p] = c * 8;
  }

  f32x4 acc[4][4];
#pragma unroll
  for (int i = 0; i < 4; ++i)
#pragma unroll
    for (int j = 0; j < 4; ++j) acc[i][j] = (f32x4){0.f, 0.f, 0.f, 0.f};

#pragma unroll
  for (int p = 0; p < 2; ++p) {
    gl_lds16(gA[p], &As[0][off[p]]);
    gl_lds16(gB[p], &Bs[0][off[p]]);
  }

  const int NIT = K >> 5;
  for (int it = 0; it < NIT; ++it) {
    __syncthreads();
    const int cur = it & 1;
    if (it + 1 < NIT) {
      const int kt = (it + 1) << 5;
#pragma unroll
      for (int p = 0; p < 2; ++p) {
        gl_lds16(gA[p] + kt, &As[cur ^ 1][off[p]]);
        gl_lds16(gB[p] + kt, &Bs[cur ^ 1][off[p]]);
      }
    }
    const unsigned short* Ac = As[cur];
    const unsigned short* Bc = Bs[cur];
    bf16x8 af[4], bfr[4];
#pragma unroll
    for (int i = 0; i < 4; ++i)
      af[i] = *(const bf16x8*)&Ac[(wy * 64 + i * 16 + l15) * 32 + (quad ^ xr2) * 8];
#pragma unroll
    for (int j = 0; j < 4; ++j)
      bfr[j] = *(const bf16x8*)&Bc[(wx * 64 + j * 16 + l15) * 32 + (quad ^ xr2) * 8];
#pragma unroll
    for (int i = 0; i < 4; ++i)
#pragma unroll
      for (int j = 0; j < 4; ++j)
        acc[i][j] = __builtin_amdgcn_mfma_f32_16x16x32_bf16(af[i], bfr[j], acc[i][j], 0, 0, 0);
  }

  const bool vblock = (n0 >= 2048);  // block-uniform
#pragma unroll
  for (int i = 0; i < 4; ++i) {
    const int row = m0 + wy * 64 + i * 16 + quad * 4;
#pragma unroll
    for (int j = 0; j < 4; ++j) {
      const int col = n0 + wx * 64 + j * 16 + l15;
      const float bv = bias[col];
      if (!vblock) {
        const float sc = (col < qcols) ? 0.125f : 1.0f;
#pragma unroll
        for (int r = 0; r < 4; ++r)
          Cb[(size_t)(row + r) * N + col] = f2b((acc[i][j][r] + bv) * sc);
      } else {
        const int hd = col - 2048;
        const int bb = row >> 11, s = row & 2047;
        u16x4 ov;
#pragma unroll
        for (int r = 0; r < 4; ++r) ov[r] = f2b(acc[i][j][r] + bv);
        *(u16x4*)(vtb + ((size_t)(bb * 1024 + hd)) * 2048 + s) = ov;
      }
    }
  }
}

// ---------------- GEMM 128x64 tile, fp32 out (O-projection) ----------------
// R23: was 64x64 (343-TF ladder point). Now BM=128,BN=64,BK=64 dbuf: per
// iter 16 MFMA / 12 frag reads per wave. Grid (16,32)=512 blocks (2/CU),
// LDS 48KB. Same XOR swizzle (row stride 64 ushorts unchanged).
__global__ __launch_bounds__(256) void gemm_bt64(const unsigned short* __restrict__ A,
                                                 const unsigned short* __restrict__ W,
                                                 const float* __restrict__ bias,
                                                 float* __restrict__ Cf,
                                                 int M, int N, int K) {
  __shared__ unsigned short As[2][128 * 64];
  __shared__ unsigned short Bs[2][64 * 64];
  const int tid  = threadIdx.x;
  const int lane = tid & 63;
  const int w    = tid >> 6;
  const int wy   = w >> 1, wx = w & 1;   // wy: m-half (64 rows), wx: n-half (32 cols)
  const int l15  = lane & 15, quad = lane >> 4;
  const int xr   = l15 & 7;
  const int m0 = blockIdx.y * 128, n0 = blockIdx.x * 64;

  // A: 128 rows x 8 chunks = 1024 chunks -> 4/thread. B: 512 chunks -> 2/thread.
  const unsigned short* gA[4];
  int offA[4];
#pragma unroll
  for (int p = 0; p < 4; ++p) {
    const int c = tid + p * 256;
    const int r = c >> 3;
    const int sc = ((c & 7) ^ (r & 7)) * 8;
    gA[p] = A + (size_t)(m0 + r) * K + sc;
    offA[p] = c * 8;
  }
  const unsigned short* gB[2];
  int offB[2];
#pragma unroll
  for (int p = 0; p < 2; ++p) {
    const int c = tid + p * 256;
    const int r = c >> 3;
    const int sc = ((c & 7) ^ (r & 7)) * 8;
    gB[p] = W + (size_t)(n0 + r) * K + sc;
    offB[p] = c * 8;
  }

  f32x4 acc[4][2];
#pragma unroll
  for (int i = 0; i < 4; ++i)
#pragma unroll
    for (int j = 0; j < 2; ++j) acc[i][j] = (f32x4){0.f, 0.f, 0.f, 0.f};

#pragma unroll
  for (int p = 0; p < 4; ++p) gl_lds16(gA[p], &As[0][offA[p]]);
#pragma unroll
  for (int p = 0; p < 2; ++p) gl_lds16(gB[p], &Bs[0][offB[p]]);

  const int NIT = K >> 6;
  for (int it = 0; it < NIT; ++it) {
    __syncthreads();
    const int cur = it & 1;
    if (it + 1 < NIT) {
      const int kt = (it + 1) << 6;
#pragma unroll
      for (int p = 0; p < 4; ++p) gl_lds16(gA[p] + kt, &As[cur ^ 1][offA[p]]);
#pragma unroll
      for (int p = 0; p < 2; ++p) gl_lds16(gB[p] + kt, &Bs[cur ^ 1][offB[p]]);
    }
    const unsigned short* Ac = As[cur];
    const unsigned short* Bc = Bs[cur];
#pragma unroll
    for (int kc = 0; kc < 2; ++kc) {
      bf16x8 af[4], bfr[2];
#pragma unroll
      for (int i = 0; i < 4; ++i)
        af[i] = *(const bf16x8*)&Ac[(wy * 64 + i * 16 + l15) * 64 + ((kc * 4 + quad) ^ xr) * 8];
#pragma unroll
      for (int j = 0; j < 2; ++j)
        bfr[j] = *(const bf16x8*)&Bc[(wx * 32 + j * 16 + l15) * 64 + ((kc * 4 + quad) ^ xr) * 8];
#pragma unroll
      for (int i = 0; i < 4; ++i)
#pragma unroll
        for (int j = 0; j < 2; ++j)
          acc[i][j] = __builtin_amdgcn_mfma_f32_16x16x32_bf16(af[i], bfr[j], acc[i][j], 0, 0, 0);
    }
  }

#pragma unroll
  for (int i = 0; i < 4; ++i) {
    const int row = m0 + wy * 64 + i * 16 + quad * 4;
#pragma unroll
    for (int j = 0; j < 2; ++j) {
      const int col = n0 + wx * 32 + j * 16 + l15;
      const float bv = bias[col];
#pragma unroll
      for (int r = 0; r < 4; ++r)
        Cf[(size_t)(row + r) * N + col] = acc[i][j][r] + bv;
    }
  }
}

// ---------------- flash attention v18: 4-wave q x kv split -----------------
// Block = 4 waves (wq,wk in 2x2), 64 q x 64 kv tiles; grid (bh 32, y 32).
// Wave (wq,wk): q-half wq (2 subtiles of 16) x kv-half wk (32 kv). Per wave
// per tile: 4 K-frags, 8 S^T MFMA, 16 exp, 4 Pw, 1 Pr + 4 V-frags, 10 PV
// MFMA — per-block LDS traffic unchanged vs v14, per-wave chain ~halved,
// 12 waves/CU. kv-half partials (acc, accL) combined once per block via the
// dead K/V LDS buffers. qt map y<16?y:47-y (R21, neutral). XCD=bh%8.
__global__ __launch_bounds__(256, 3) void attn_fwd(const unsigned short* __restrict__ qkv,
                                                   const unsigned short* __restrict__ vt,
                                                   unsigned short* __restrict__ o) {
  __shared__ unsigned short Ks[2][64 * 64];
  __shared__ unsigned short Vs[2][64 * 64];
  __shared__ unsigned short pbuf[4][2][16 * 40];  // [wave][subtile][16 x (32+8)]
  const int tid  = threadIdx.x;
  const int lane = tid & 63;
  const int w    = tid >> 6;          // 4 waves
  const int wq   = w & 1;             // q-half (32 q)
  const int wk   = w >> 1;            // kv-half (32 kv)
  const int l15  = lane & 15, quad = lane >> 4;
  const int xr   = l15 & 7;
  const int bh = blockIdx.x, b = bh >> 4, h = bh & 15;
  const int y  = (int)blockIdx.y;
  const int qt = (y < 16) ? y : 47 - y;  // per-CU balanced (R21)
  const int q0 = qt * 64;
  const int T = qt + 1;
  const int qs0 = q0 + wq * 32;       // subtile 0 base
  const int qs1 = qs0 + 16;           // subtile 1 base

  // DMA staging: 512 chunks per 64x64 tile / 256 threads = 2/thread/array.
  const unsigned short* gKd[2];
  const unsigned short* gVd[2];
  int doff[2];
#pragma unroll
  for (int p = 0; p < 2; ++p) {
    const int c = tid + p * 256;
    const int r = c >> 3;
    const int sc = ((c & 7) ^ (r & 7)) * 8;
    gKd[p] = qkv + (size_t)(b * 2048 + r) * 3072 + 1024 + h * 64 + sc;
    gVd[p] = vt + (size_t)(bh * 64 + r) * 2048 + sc;
    doff[p] = c * 8;
  }

  const unsigned short* qr0 = qkv + (size_t)(b * 2048 + qs0 + l15) * 3072 + h * 64;
  const unsigned short* qr1 = qkv + (size_t)(b * 2048 + qs1 + l15) * 3072 + h * 64;
  const bf16x8 bq[2][2] = {
    { *(const bf16x8*)(qr0 + quad * 8), *(const bf16x8*)(qr0 + 32 + quad * 8) },
    { *(const bf16x8*)(qr1 + quad * 8), *(const bf16x8*)(qr1 + 32 + quad * 8) } };

  bf16x8 vones;
#pragma unroll
  for (int k = 0; k < 8; ++k) vones[k] = (short)0x3F80;  // bf16 1.0

  f32x4 acc[2][4];   // [subtile][d-tile], PARTIAL over this wave's kv-half
#pragma unroll
  for (int i = 0; i < 2; ++i)
#pragma unroll
    for (int j = 0; j < 4; ++j) acc[i][j] = (f32x4){0.f, 0.f, 0.f, 0.f};
  f32x4 accL[2] = {(f32x4){0.f, 0.f, 0.f, 0.f}, (f32x4){0.f, 0.f, 0.f, 0.f}};

  unsigned short* P0 = pbuf[w][0];
  unsigned short* P1 = pbuf[w][1];

  // prologue: DMA tile 0 -> buf 0
#pragma unroll
  for (int p = 0; p < 2; ++p) {
    gl_lds16(gKd[p], &Ks[0][doff[p]]);
    gl_lds16(gVd[p], &Vs[0][doff[p]]);
  }

  for (int t = 0; t < T; ++t) {
    __syncthreads();  // drains DMA for buf(t&1)
    const int cur = t & 1;
    if (t + 1 < T) {
      const size_t ko = (size_t)(t + 1) * 64 * 3072;
      const int vo = (t + 1) * 64;
#pragma unroll
      for (int p = 0; p < 2; ++p) {
        gl_lds16(gKd[p] + ko, &Ks[cur ^ 1][doff[p]]);
        gl_lds16(gVd[p] + vo, &Vs[cur ^ 1][doff[p]]);
      }
    }
    const unsigned short* Kc = Ks[cur];
    const unsigned short* Vc = Vs[cur];
    const int kv0 = t * 64 + wk * 32;   // this wave's kv base

    // ---- S^T[kv][q] = K Q^T, this wave's 32 kv x 32 q ----
    bf16x8 kA[2][2];
#pragma unroll
    for (int n = 0; n < 2; ++n) {
      const int row = wk * 32 + n * 16 + l15;
      kA[n][0] = *(const bf16x8*)&Kc[row * 64 + ((quad) ^ xr) * 8];
      kA[n][1] = *(const bf16x8*)&Kc[row * 64 + ((4 + quad) ^ xr) * 8];
    }
    f32x4 st[2][2];
#pragma unroll
    for (int s = 0; s < 2; ++s)
#pragma unroll
      for (int n = 0; n < 2; ++n) {
        f32x4 z = (f32x4){0.f, 0.f, 0.f, 0.f};
        z = __builtin_amdgcn_mfma_f32_16x16x32_bf16(kA[n][0], bq[s][0], z, 0, 0, 0);
        z = __builtin_amdgcn_mfma_f32_16x16x32_bf16(kA[n][1], bq[s][1], z, 0, 0, 0);
        st[s][n] = z;
      }
    // ---- V^T A-frags for this kv-half ----
    bf16x8 av[4];
#pragma unroll
    for (int j = 0; j < 4; ++j) {
      const int row = j * 16 + l15;
      av[j] = *(const bf16x8*)&Vc[row * 64 + ((wk * 4 + quad) ^ xr) * 8];
    }
    // ---- mask/exp + P writes for both subtiles ----
#pragma unroll
    for (int s = 0; s < 2; ++s) {
      unsigned short* P = s ? P1 : P0;
      const int qbase = s ? qs1 : qs0;
      if (kv0 + 31 > qbase) {
        const int qrow = qbase + l15;
#pragma unroll
        for (int n = 0; n < 2; ++n)
#pragma unroll
          for (int r = 0; r < 4; ++r)
            if (kv0 + n * 16 + quad * 4 + r > qrow) st[s][n][r] = -1e30f;
      }
#pragma unroll
      for (int n = 0; n < 2; ++n) {
#pragma unroll
        for (int r = 0; r < 4; ++r) st[s][n][r] = __expf(st[s][n][r]);
        u16x4 pw;
        pw[0] = f2b_trunc(st[s][n][0]); pw[1] = f2b_trunc(st[s][n][1]);
        pw[2] = f2b_trunc(st[s][n][2]); pw[3] = f2b_trunc(st[s][n][3]);
        *(u16x4*)&P[l15 * 40 + n * 16 + quad * 4] = pw;
      }
    }
    // ---- Pr + PV (K=32 contraction = exactly one MFMA per (s,j)) ----
#pragma unroll
    for (int s = 0; s < 2; ++s) {
      const unsigned short* P = s ? P1 : P0;
      const bf16x8 bp = *(const bf16x8*)&P[l15 * 40 + quad * 8];
      accL[s] = __builtin_amdgcn_mfma_f32_16x16x32_bf16(vones, bp, accL[s], 0, 0, 0);
#pragma unroll
      for (int j = 0; j < 4; ++j)
        acc[s][j] = __builtin_amdgcn_mfma_f32_16x16x32_bf16(av[j], bp, acc[s][j], 0, 0, 0);
    }
  }

  // ---- cross-wave kv-half combine (once per block; K/V buffers are dead) --
  __syncthreads();
  float* cmbA = (float*)&Ks[0][0];   // 16 frags x 256 floats = 16KB = Ks
  float* cmbL = (float*)&Vs[0][0];   // 4 x 64 floats = 1KB
  if (wk == 1) {
#pragma unroll
    for (int s = 0; s < 2; ++s) {
      cmbL[(wq * 2 + s) * 64 + lane] = accL[s][0];
#pragma unroll
      for (int j = 0; j < 4; ++j)
        *(f32x4*)&cmbA[(((wq * 2 + s) * 4 + j) << 8) + lane * 4] = acc[s][j];
    }
  }
  __syncthreads();
  if (wk == 0) {
#pragma unroll
    for (int s = 0; s < 2; ++s) {
      const float lsum = accL[s][0] + cmbL[(wq * 2 + s) * 64 + lane];
      const float inv = 1.0f / lsum;
      const int qrow = (s ? qs1 : qs0) + l15;
      unsigned short* orow = o + (size_t)(b * 2048 + qrow) * 1024 + h * 64;
#pragma unroll
      for (int j = 0; j < 4; ++j) {
        const f32x4 oth = *(const f32x4*)&cmbA[(((wq * 2 + s) * 4 + j) << 8) + lane * 4];
        u16x4 ov;
        ov[0] = f2b((acc[s][j][0] + oth[0]) * inv);
        ov[1] = f2b((acc[s][j][1] + oth[1]) * inv);
        ov[2] = f2b((acc[s][j][2] + oth[2]) * inv);
        ov[3] = f2b((acc[s][j][3] + oth[3]) * inv);
        *(u16x4*)(orow + j * 16 + quad * 4) = ov;
      }
    }
  }
}

// ---------------------------------------------------------------------------
extern "C" void kernel_launch(void* const* d_in, const int* in_sizes, int n_in,
                              void* d_out, int out_size, void* d_ws, size_t ws_size,
                              hipStream_t stream) {
  const float* x       = (const float*)d_in[0];
  // d_in[1] = mask: causal tril by construction; implemented analytically.
  const float* w_qkv_w = (const float*)d_in[2];
  const float* w_qkv_b = (const float*)d_in[3];
  const float* w_o_w   = (const float*)d_in[4];
  const float* w_o_b   = (const float*)d_in[5];
  float* out = (float*)d_out;

  unsigned short* ws    = (unsigned short*)d_ws;
  unsigned short* xb    = ws;                                  // 4096*1024
  unsigned short* wqb   = xb   + (size_t)4096 * 1024;          // 3072*1024
  unsigned short* wob   = wqb  + (size_t)3072 * 1024;          // 1024*1024
  unsigned short* qkvb  = wob  + (size_t)1024 * 1024;          // 4096*3072
  unsigned short* vtb   = qkvb + (size_t)4096 * 3072;          // 2048*2048
  unsigned short* attnb = vtb  + (size_t)2048 * 2048;          // 4096*1024

  cvt_all<<<8192, 256, 0, stream>>>(x, w_qkv_w, w_o_w, xb, wqb, wob);
  gemm_bt<<<dim3(24, 32), 256, 0, stream>>>(xb, wqb, w_qkv_b, qkvb, vtb, 4096, 3072, 1024, 1024);
  attn_fwd<<<dim3(32, 32), 256, 0, stream>>>(qkvb, vtb, attnb);
  gemm_bt64<<<dim3(16, 32), 256, 0, stream>>>(attnb, wob, w_o_b, out, 4096, 1024, 1024);
}